// Round 20
// baseline (117.668 us; speedup 1.0000x reference)
//
#include <hip/hip_runtime.h>
#include <math.h>

#define N_NODES 50000
#define E_EDGES 800000
#define D_FEAT  64
#define C_CH    3
#define H_HID   8
#define OUT_F   128
#define CD      192              // C*D
#define NTILES  (N_NODES / 16)   // 3125 exact
#define NBLK_SCAN ((N_NODES + 255) / 256)   // 196
#define XCVT_BLOCKS (N_NODES * D_FEAT / 4 / 256)   // 3125
#define EDGE_BLOCKS (E_EDGES / 256)                // 3125
#define RANK_BLOCKS ((E_EDGES + 1023) / 1024)      // 782
#define NREP 8

typedef _Float16 half8 __attribute__((ext_vector_type(8)));
typedef _Float16 half4 __attribute__((ext_vector_type(4)));
typedef float f32x4 __attribute__((ext_vector_type(4)));

__device__ __forceinline__ float lrelu(float v) { return v >= 0.f ? v : 0.01f * v; }

__device__ __forceinline__ unsigned short f2h_bits(float f) {
    _Float16 h = (_Float16)f;
    unsigned short b;
    __builtin_memcpy(&b, &h, 2);
    return b;
}
__device__ __forceinline__ float h2f_bits(unsigned b) {
    unsigned short s = (unsigned short)b;
    _Float16 h;
    __builtin_memcpy(&h, &s, 2);
    return (float)h;
}

// --- K1: pure-stream {x f32->f16} + {edge MLP -> wbuf}. NO atomics. ---------
__global__ __launch_bounds__(256) void k_pre(
    const float* __restrict__ x, _Float16* __restrict__ xh,
    const int* __restrict__ ei, const float* __restrict__ ea,
    const float* __restrict__ w1, const float* __restrict__ b1,
    const float* __restrict__ w2, const float* __restrict__ b2,
    uint2* __restrict__ wbuf)
{
    if (blockIdx.x < XCVT_BLOCKS) {
        int i = blockIdx.x * 256 + threadIdx.x;
        float4 f = ((const float4*)x)[i];
        half4 h;
        h[0] = (_Float16)f.x; h[1] = (_Float16)f.y;
        h[2] = (_Float16)f.z; h[3] = (_Float16)f.w;
        *(half4*)(xh + (size_t)i * 4) = h;
        return;
    }
    int e = (blockIdx.x - XCVT_BLOCKS) * 256 + threadIdx.x;
    int src = ei[e];
    float a = ea[e];
    float wc[C_CH];
#pragma unroll
    for (int c = 0; c < C_CH; ++c) {
        float s = 0.f;
#pragma unroll
        for (int h = 0; h < H_HID; ++h) {
            float t = fmaf(a, w1[c * H_HID + h], b1[c * H_HID + h]);
            t = (t >= 0.f) ? t : 0.01f * t;               // leaky_relu
            s = fmaf(t, w2[c * H_HID + h], s);
        }
        s += b2[c];
        wc[c] = (s > 0.f) ? s : expm1f(s);                // elu
    }
    uint2 r;
    r.x = (unsigned)src | ((unsigned)f2h_bits(wc[0]) << 16);
    r.y = (unsigned)f2h_bits(wc[1]) | ((unsigned)f2h_bits(wc[2]) << 16);
    wbuf[e] = r;
}

// --- K1b: rank kernel — 4 independent atomic chains per thread --------------
// g = blockIdx&7 selects the XCD-group count replica. ranks packed 4x u16
// into one 8B store. Nothing else in the kernel -> atomic latency is hidden
// purely by TLP x 4-way ILP.
__global__ __launch_bounds__(256) void k_rank(
    const int* __restrict__ ei, unsigned short* __restrict__ rank,
    int* __restrict__ counts8)
{
    const int g  = blockIdx.x & 7;
    const int e0 = blockIdx.x * 1024 + threadIdx.x * 4;
    const int* dstp = ei + E_EDGES;
    int* cb = counts8 + g * N_NODES;

    if (e0 + 3 < E_EDGES) {
        int4 d = *(const int4*)(dstp + e0);
        unsigned r0 = (unsigned)atomicAdd(cb + d.x, 1);
        unsigned r1 = (unsigned)atomicAdd(cb + d.y, 1);
        unsigned r2 = (unsigned)atomicAdd(cb + d.z, 1);
        unsigned r3 = (unsigned)atomicAdd(cb + d.w, 1);
        ushort4 rr;
        rr.x = (unsigned short)r0; rr.y = (unsigned short)r1;
        rr.z = (unsigned short)r2; rr.w = (unsigned short)r3;
        *(ushort4*)(rank + e0) = rr;
    } else {
#pragma unroll
        for (int j = 0; j < 4; ++j) {
            int e = e0 + j;
            if (e < E_EDGES)
                rank[e] = (unsigned short)atomicAdd(cb + dstp[e], 1);
        }
    }
}

// --- K2a: per-block sums of total counts (sum over 8 replicas) --------------
__global__ __launch_bounds__(256) void k_blocksum(
    const int* __restrict__ counts8, int* __restrict__ blocksums)
{
    __shared__ int s[256];
    int i = blockIdx.x * 256 + threadIdx.x;
    int t = 0;
    if (i < N_NODES)
#pragma unroll
        for (int g = 0; g < NREP; ++g) t += counts8[g * N_NODES + i];
    s[threadIdx.x] = t;
    __syncthreads();
    for (int off = 128; off >= 1; off >>= 1) {
        if (threadIdx.x < off) s[threadIdx.x] += s[threadIdx.x + off];
        __syncthreads();
    }
    if (threadIdx.x == 0) blocksums[blockIdx.x] = s[0];
}

// --- K2b: scan -> offsets[n] + per-replica bases repl_base[g][n] ------------
__global__ __launch_bounds__(256) void k_scanfinal(
    const int* __restrict__ counts8, const int* __restrict__ blocksums,
    int* __restrict__ offsets, int* __restrict__ repl_base)
{
    __shared__ int bs[256];
    __shared__ int s[256];
    const int tid = threadIdx.x;

    bs[tid] = (tid < NBLK_SCAN) ? blocksums[tid] : 0;
    __syncthreads();
    for (int off = 1; off < 256; off <<= 1) {
        int t = (tid >= off) ? bs[tid - off] : 0;
        __syncthreads();
        bs[tid] += t;
        __syncthreads();
    }
    const int blockoff = (blockIdx.x == 0) ? 0 : bs[blockIdx.x - 1];

    int i = blockIdx.x * 256 + tid;
    int cg[NREP];
    int v = 0;
    if (i < N_NODES) {
#pragma unroll
        for (int g = 0; g < NREP; ++g) {
            cg[g] = counts8[g * N_NODES + i];
            v += cg[g];
        }
    }
    s[tid] = v;
    __syncthreads();
    for (int off = 1; off < 256; off <<= 1) {
        int t = (tid >= off) ? s[tid - off] : 0;
        __syncthreads();
        s[tid] += t;
        __syncthreads();
    }
    if (i < N_NODES) {
        int excl = s[tid] - v + blockoff;      // exclusive global offset
        offsets[i] = excl;
        int run = excl;
#pragma unroll
        for (int g = 0; g < NREP; ++g) {
            repl_base[g * N_NODES + i] = run;
            run += cg[g];
        }
    }
}

// --- K3: rank-based scatter — NO atomics, 1 edge/thread ---------------------
// pos = repl_base[g(e)][dst] + rank[e]; g(e) = k_rank's blockIdx&7 = (e>>10)&7.
__global__ __launch_bounds__(256) void k_scat(
    const int* __restrict__ ei, const unsigned short* __restrict__ rank,
    const uint2* __restrict__ wbuf, const int* __restrict__ repl_base,
    uint2* __restrict__ sorted)
{
    int e = blockIdx.x * 256 + threadIdx.x;    // grid covers E exactly
    int d = ei[E_EDGES + e];
    int g = (e >> 10) & 7;                     // k_rank's blockIdx & 7
    int pos = repl_base[g * N_NODES + d] + (int)rank[e];
    sorted[pos] = wbuf[e];                     // 8B scatter, no dependency
}

// --- K4: gather (f16 x rows) + residual -> v[N][192] f16 --------------------
__global__ __launch_bounds__(256) void k_gather(
    const uint2* __restrict__ sorted, const int* __restrict__ offsets,
    const _Float16* __restrict__ xh, const float* __restrict__ x,
    const float* __restrict__ eps, _Float16* __restrict__ v)
{
    const int n    = blockIdx.x * 4 + (threadIdx.x >> 6);   // grid = N/4 exact
    const int lane = threadIdx.x & 63;

    const int start = offsets[n];
    const int end   = (n + 1 < N_NODES) ? offsets[n + 1] : E_EDGES;

    float a0 = 0.f, a1 = 0.f, a2 = 0.f;
    float b0 = 0.f, b1 = 0.f, b2 = 0.f;
    float c0 = 0.f, c1 = 0.f, c2 = 0.f;
    float d0 = 0.f, d1 = 0.f, d2 = 0.f;

    for (int base = start; base < end; base += 64) {
        const int m = min(64, end - base);
        uint2 rec = make_uint2(0u, 0u);
        if (lane < m) rec = sorted[base + lane];     // coalesced 8B
        int j = 0;
        for (; j + 4 <= m; j += 4) {
            unsigned rxA = (unsigned)__shfl((int)rec.x, j);
            unsigned ryA = (unsigned)__shfl((int)rec.y, j);
            unsigned rxB = (unsigned)__shfl((int)rec.x, j + 1);
            unsigned ryB = (unsigned)__shfl((int)rec.y, j + 1);
            unsigned rxC = (unsigned)__shfl((int)rec.x, j + 2);
            unsigned ryC = (unsigned)__shfl((int)rec.y, j + 2);
            unsigned rxD = (unsigned)__shfl((int)rec.x, j + 3);
            unsigned ryD = (unsigned)__shfl((int)rec.y, j + 3);
            float xA = (float)xh[(size_t)(rxA & 0xFFFFu) * D_FEAT + lane];
            float xB = (float)xh[(size_t)(rxB & 0xFFFFu) * D_FEAT + lane];
            float xC = (float)xh[(size_t)(rxC & 0xFFFFu) * D_FEAT + lane];
            float xD = (float)xh[(size_t)(rxD & 0xFFFFu) * D_FEAT + lane];
            a0 = fmaf(h2f_bits(rxA >> 16),     xA, a0);
            a1 = fmaf(h2f_bits(ryA & 0xFFFFu), xA, a1);
            a2 = fmaf(h2f_bits(ryA >> 16),     xA, a2);
            b0 = fmaf(h2f_bits(rxB >> 16),     xB, b0);
            b1 = fmaf(h2f_bits(ryB & 0xFFFFu), xB, b1);
            b2 = fmaf(h2f_bits(ryB >> 16),     xB, b2);
            c0 = fmaf(h2f_bits(rxC >> 16),     xC, c0);
            c1 = fmaf(h2f_bits(ryC & 0xFFFFu), xC, c1);
            c2 = fmaf(h2f_bits(ryC >> 16),     xC, c2);
            d0 = fmaf(h2f_bits(rxD >> 16),     xD, d0);
            d1 = fmaf(h2f_bits(ryD & 0xFFFFu), xD, d1);
            d2 = fmaf(h2f_bits(ryD >> 16),     xD, d2);
        }
        for (; j < m; ++j) {
            unsigned rx0 = (unsigned)__shfl((int)rec.x, j);
            unsigned ry0 = (unsigned)__shfl((int)rec.y, j);
            float xa = (float)xh[(size_t)(rx0 & 0xFFFFu) * D_FEAT + lane];
            a0 = fmaf(h2f_bits(rx0 >> 16),     xa, a0);
            a1 = fmaf(h2f_bits(ry0 & 0xFFFFu), xa, a1);
            a2 = fmaf(h2f_bits(ry0 >> 16),     xa, a2);
        }
    }
    a0 += b0 + c0 + d0;
    a1 += b1 + c1 + d1;
    a2 += b2 + c2 + d2;

    float xn = x[(size_t)n * D_FEAT + lane];
    _Float16* vr = v + (size_t)n * CD;
    vr[lane]       = (_Float16)(a0 + (1.f + eps[0]) * xn);
    vr[64 + lane]  = (_Float16)(a1 + (1.f + eps[1]) * xn);
    vr[128 + lane] = (_Float16)(a2 + (1.f + eps[2]) * xn);
}

// --- K5: MLP1(lrelu) + MLP2 via f16 MFMA ------------------------------------
__global__ __launch_bounds__(256) void k_mlp(
    const _Float16* __restrict__ v,
    const float* __restrict__ nw1, const float* __restrict__ nb1,
    const float* __restrict__ nw2, const float* __restrict__ nb2,
    float* __restrict__ out)
{
    __shared__ _Float16 vtile[16][CD + 8];     // stride 400B (16B mult)
    __shared__ _Float16 htile[16][OUT_F + 8];  // stride 272B (16B mult)

    const int tid  = threadIdx.x;
    const int lane = tid & 63;
    const int wid  = tid >> 6;
    const int arow = lane & 15;
    const int kg   = lane >> 4;
    const int o0   = wid * 32;

    half8 w1f[6][2], w2f[4][2];
#pragma unroll
    for (int kk = 0; kk < 6; ++kk)
#pragma unroll
        for (int nt = 0; nt < 2; ++nt) {
            half8 f;
            int colb = o0 + nt * 16 + arow;
            int kb = kk * 32 + kg * 8;
#pragma unroll
            for (int j = 0; j < 8; ++j)
                f[j] = (_Float16)nw1[(size_t)(kb + j) * OUT_F + colb];
            w1f[kk][nt] = f;
        }
#pragma unroll
    for (int kk = 0; kk < 4; ++kk)
#pragma unroll
        for (int nt = 0; nt < 2; ++nt) {
            half8 f;
            int colb = o0 + nt * 16 + arow;
            int kb = kk * 32 + kg * 8;
#pragma unroll
            for (int j = 0; j < 8; ++j)
                f[j] = (_Float16)nw2[(size_t)(kb + j) * OUT_F + colb];
            w2f[kk][nt] = f;
        }

    const float b1a = nb1[o0 + arow],      b1b = nb1[o0 + 16 + arow];
    const float b2a = nb2[o0 + arow],      b2b = nb2[o0 + 16 + arow];

    for (int t = blockIdx.x; t < NTILES; t += gridDim.x) {
        const int nb16 = t * 16;
        __syncthreads();

        for (int i = tid; i < 16 * (CD / 8); i += 256) {    // 384 chunks
            int row = i / (CD / 8), c8 = i % (CD / 8);
            *(half8*)&vtile[row][c8 * 8] =
                *(const half8*)(v + (size_t)(nb16 + row) * CD + c8 * 8);
        }
        __syncthreads();

        f32x4 acc0 = {0.f, 0.f, 0.f, 0.f}, acc1 = {0.f, 0.f, 0.f, 0.f};
#pragma unroll
        for (int kk = 0; kk < 6; ++kk) {
            half8 a = *(const half8*)&vtile[arow][kk * 32 + kg * 8];
            acc0 = __builtin_amdgcn_mfma_f32_16x16x32_f16(a, w1f[kk][0], acc0, 0, 0, 0);
            acc1 = __builtin_amdgcn_mfma_f32_16x16x32_f16(a, w1f[kk][1], acc1, 0, 0, 0);
        }
#pragma unroll
        for (int r = 0; r < 4; ++r) {
            int hr = kg * 4 + r;
            htile[hr][o0 + arow]      = (_Float16)lrelu(acc0[r] + b1a);
            htile[hr][o0 + 16 + arow] = (_Float16)lrelu(acc1[r] + b1b);
        }
        __syncthreads();

        f32x4 c0 = {0.f, 0.f, 0.f, 0.f}, c1 = {0.f, 0.f, 0.f, 0.f};
#pragma unroll
        for (int kk = 0; kk < 4; ++kk) {
            half8 a = *(const half8*)&htile[arow][kk * 32 + kg * 8];
            c0 = __builtin_amdgcn_mfma_f32_16x16x32_f16(a, w2f[kk][0], c0, 0, 0, 0);
            c1 = __builtin_amdgcn_mfma_f32_16x16x32_f16(a, w2f[kk][1], c1, 0, 0, 0);
        }
#pragma unroll
        for (int r = 0; r < 4; ++r) {
            size_t n = (size_t)(nb16 + kg * 4 + r);
            out[n * OUT_F + o0 + arow]      = c0[r] + b2a;
            out[n * OUT_F + o0 + 16 + arow] = c1[r] + b2b;
        }
    }
}

extern "C" void kernel_launch(void* const* d_in, const int* in_sizes, int n_in,
                              void* d_out, int out_size, void* d_ws, size_t ws_size,
                              hipStream_t stream)
{
    const float* x    = (const float*)d_in[0];
    const int*   ei   = (const int*)  d_in[1];
    const float* ea   = (const float*)d_in[2];
    const float* w1   = (const float*)d_in[3];
    const float* b1   = (const float*)d_in[4];
    const float* w2   = (const float*)d_in[5];
    const float* b2   = (const float*)d_in[6];
    const float* eps  = (const float*)d_in[7];
    const float* nw1  = (const float*)d_in[8];
    const float* nb1  = (const float*)d_in[9];
    const float* nw2  = (const float*)d_in[10];
    const float* nb2  = (const float*)d_in[11];
    float* out = (float*)d_out;

    // ws layout (bytes): total ~37.0 MB <= proven 38.4 MB
    char* ws = (char*)d_ws;
    int*            counts8   = (int*)           (ws + 0);          // 1,600,000
    int*            blocksums = (int*)           (ws + 1600000);    // 784
    int*            offsets   = (int*)           (ws + 1604096);    // 200,000
    int*            repl_base = (int*)           (ws + 1804800);    // 1,600,000
    unsigned short* rank      = (unsigned short*)(ws + 3404800);    // 1,600,000
    uint2*          wbuf      = (uint2*)         (ws + 5004800);    // 6,400,000
    uint2*          sorted    = (uint2*)         (ws + 11404800);   // 6,400,000
    _Float16*       v         = (_Float16*)      (ws + 17804800);   // 19,200,000

    // xh lives in d_out (6.4 MB of 25.6 MB); dead before k_mlp overwrites
    // (proven safe in rounds 14/18/19)
    _Float16* xh = (_Float16*)d_out;

    hipMemsetAsync(counts8, 0, NREP * N_NODES * sizeof(int), stream);

    k_pre      <<<XCVT_BLOCKS + EDGE_BLOCKS, 256, 0, stream>>>(
        x, xh, ei, ea, w1, b1, w2, b2, wbuf);
    k_rank     <<<RANK_BLOCKS, 256, 0, stream>>>(ei, rank, counts8);
    k_blocksum <<<NBLK_SCAN,   256, 0, stream>>>(counts8, blocksums);
    k_scanfinal<<<NBLK_SCAN,   256, 0, stream>>>(counts8, blocksums, offsets, repl_base);
    k_scat     <<<EDGE_BLOCKS, 256, 0, stream>>>(ei, rank, wbuf, repl_base, sorted);
    k_gather   <<<N_NODES / 4, 256, 0, stream>>>(sorted, offsets, xh, x, eps, v);
    k_mlp      <<<768,         256, 0, stream>>>(v, nw1, nb1, nw2, nb2, out);
}

// Round 21
// 114.532 us; speedup vs baseline: 1.0274x; 1.0274x over previous
//
#include <hip/hip_runtime.h>
#include <math.h>

#define N_NODES 50000
#define E_EDGES 800000
#define D_FEAT  64
#define C_CH    3
#define H_HID   8
#define OUT_F   128
#define CD      192              // C*D
#define NTILES  (N_NODES / 16)   // 3125 exact
#define NBLK_SCAN ((N_NODES + 255) / 256)   // 196
#define XCVT_BLOCKS (N_NODES * D_FEAT / 4 / 256)   // 3125
#define EDGE_BLOCKS ((E_EDGES + 1023) / 1024)      // 782 (4 edges/thread)
#define SCAT_BLOCKS (E_EDGES / 256)                // 3125
#define NREP 8

typedef _Float16 half8 __attribute__((ext_vector_type(8)));
typedef _Float16 half4 __attribute__((ext_vector_type(4)));
typedef float f32x4 __attribute__((ext_vector_type(4)));

__device__ __forceinline__ float lrelu(float v) { return v >= 0.f ? v : 0.01f * v; }

__device__ __forceinline__ unsigned short f2h_bits(float f) {
    _Float16 h = (_Float16)f;
    unsigned short b;
    __builtin_memcpy(&b, &h, 2);
    return b;
}
__device__ __forceinline__ float h2f_bits(unsigned b) {
    unsigned short s = (unsigned short)b;
    _Float16 h;
    __builtin_memcpy(&h, &s, 2);
    return (float)h;
}

__device__ __forceinline__ float edge_mlp(
    float a, const float* __restrict__ w1, const float* __restrict__ b1,
    const float* __restrict__ w2, float b2c, int c)
{
    float s = 0.f;
#pragma unroll
    for (int h = 0; h < H_HID; ++h) {
        float t = fmaf(a, w1[c * H_HID + h], b1[c * H_HID + h]);
        t = (t >= 0.f) ? t : 0.01f * t;               // leaky_relu
        s = fmaf(t, w2[c * H_HID + h], s);
    }
    s += b2c;
    return (s > 0.f) ? s : expm1f(s);                 // elu
}

// --- K1: fused {x f32->f16} + {4-edge/thread MLP + wbuf + XCD-local rank} ---
// 4 independent atomic-with-return chains per thread; chain latency hides
// under the 4 dense MLPs + neighbor waves' stream work (round-19 fusion win
// + 4x ILP). ranks packed into one ushort4 store.
__global__ __launch_bounds__(256) void k_pre(
    const float* __restrict__ x, _Float16* __restrict__ xh,
    const int* __restrict__ ei, const float* __restrict__ ea,
    const float* __restrict__ w1, const float* __restrict__ b1,
    const float* __restrict__ w2, const float* __restrict__ b2,
    uint2* __restrict__ wbuf, unsigned short* __restrict__ rank,
    int* __restrict__ counts8)
{
    if (blockIdx.x < XCVT_BLOCKS) {
        int i = blockIdx.x * 256 + threadIdx.x;
        float4 f = ((const float4*)x)[i];
        half4 h;
        h[0] = (_Float16)f.x; h[1] = (_Float16)f.y;
        h[2] = (_Float16)f.z; h[3] = (_Float16)f.w;
        *(half4*)(xh + (size_t)i * 4) = h;
        return;
    }
    const int g  = blockIdx.x & 7;                 // round-robin XCD id
    const int e0 = (blockIdx.x - XCVT_BLOCKS) * 1024 + threadIdx.x * 4;
    const int* dstp = ei + E_EDGES;
    int* cb = counts8 + g * N_NODES;
    const float b20 = b2[0], b21 = b2[1], b22 = b2[2];

    if (e0 + 3 < E_EDGES) {
        int4   sv = *(const int4*)(ei + e0);
        int4   d  = *(const int4*)(dstp + e0);
        float4 a  = *(const float4*)(ea + e0);

        // 4 independent atomic chains, issued up front
        unsigned r0 = (unsigned)atomicAdd(cb + d.x, 1);
        unsigned r1 = (unsigned)atomicAdd(cb + d.y, 1);
        unsigned r2 = (unsigned)atomicAdd(cb + d.z, 1);
        unsigned r3 = (unsigned)atomicAdd(cb + d.w, 1);

        uint2 rec[4];
        int   se[4] = {sv.x, sv.y, sv.z, sv.w};
        float av[4] = {a.x, a.y, a.z, a.w};
#pragma unroll
        for (int j = 0; j < 4; ++j) {
            float w0 = edge_mlp(av[j], w1, b1, w2, b20, 0);
            float wA = edge_mlp(av[j], w1, b1, w2, b21, 1);
            float wB = edge_mlp(av[j], w1, b1, w2, b22, 2);
            rec[j].x = (unsigned)se[j] | ((unsigned)f2h_bits(w0) << 16);
            rec[j].y = (unsigned)f2h_bits(wA) | ((unsigned)f2h_bits(wB) << 16);
        }
        *(uint4*)(wbuf + e0)     = make_uint4(rec[0].x, rec[0].y, rec[1].x, rec[1].y);
        *(uint4*)(wbuf + e0 + 2) = make_uint4(rec[2].x, rec[2].y, rec[3].x, rec[3].y);
        ushort4 rr;
        rr.x = (unsigned short)r0; rr.y = (unsigned short)r1;
        rr.z = (unsigned short)r2; rr.w = (unsigned short)r3;
        *(ushort4*)(rank + e0) = rr;
    } else {
#pragma unroll
        for (int j = 0; j < 4; ++j) {
            int e = e0 + j;
            if (e < E_EDGES) {
                float aa = ea[e];
                float w0 = edge_mlp(aa, w1, b1, w2, b20, 0);
                float wA = edge_mlp(aa, w1, b1, w2, b21, 1);
                float wB = edge_mlp(aa, w1, b1, w2, b22, 2);
                uint2 r;
                r.x = (unsigned)ei[e] | ((unsigned)f2h_bits(w0) << 16);
                r.y = (unsigned)f2h_bits(wA) | ((unsigned)f2h_bits(wB) << 16);
                wbuf[e] = r;
                rank[e] = (unsigned short)atomicAdd(cb + dstp[e], 1);
            }
        }
    }
}

// --- K2a: per-block sums of total counts (sum over 8 replicas) --------------
__global__ __launch_bounds__(256) void k_blocksum(
    const int* __restrict__ counts8, int* __restrict__ blocksums)
{
    __shared__ int s[256];
    int i = blockIdx.x * 256 + threadIdx.x;
    int t = 0;
    if (i < N_NODES)
#pragma unroll
        for (int g = 0; g < NREP; ++g) t += counts8[g * N_NODES + i];
    s[threadIdx.x] = t;
    __syncthreads();
    for (int off = 128; off >= 1; off >>= 1) {
        if (threadIdx.x < off) s[threadIdx.x] += s[threadIdx.x + off];
        __syncthreads();
    }
    if (threadIdx.x == 0) blocksums[blockIdx.x] = s[0];
}

// --- K2b: scan -> offsets[n] + per-replica bases repl_base[g][n] ------------
__global__ __launch_bounds__(256) void k_scanfinal(
    const int* __restrict__ counts8, const int* __restrict__ blocksums,
    int* __restrict__ offsets, int* __restrict__ repl_base)
{
    __shared__ int bs[256];
    __shared__ int s[256];
    const int tid = threadIdx.x;

    bs[tid] = (tid < NBLK_SCAN) ? blocksums[tid] : 0;
    __syncthreads();
    for (int off = 1; off < 256; off <<= 1) {
        int t = (tid >= off) ? bs[tid - off] : 0;
        __syncthreads();
        bs[tid] += t;
        __syncthreads();
    }
    const int blockoff = (blockIdx.x == 0) ? 0 : bs[blockIdx.x - 1];

    int i = blockIdx.x * 256 + tid;
    int cg[NREP];
    int v = 0;
    if (i < N_NODES) {
#pragma unroll
        for (int g = 0; g < NREP; ++g) {
            cg[g] = counts8[g * N_NODES + i];
            v += cg[g];
        }
    }
    s[tid] = v;
    __syncthreads();
    for (int off = 1; off < 256; off <<= 1) {
        int t = (tid >= off) ? s[tid - off] : 0;
        __syncthreads();
        s[tid] += t;
        __syncthreads();
    }
    if (i < N_NODES) {
        int excl = s[tid] - v + blockoff;      // exclusive global offset
        offsets[i] = excl;
        int run = excl;
#pragma unroll
        for (int g = 0; g < NREP; ++g) {
            repl_base[g * N_NODES + i] = run;
            run += cg[g];
        }
    }
}

// --- K3: rank-based scatter — NO atomics, 1 edge/thread ---------------------
// pos = repl_base[g(e)][dst] + rank[e]; g(e) = k_pre's edge-block blockIdx&7.
__global__ __launch_bounds__(256) void k_scat(
    const int* __restrict__ ei, const unsigned short* __restrict__ rank,
    const uint2* __restrict__ wbuf, const int* __restrict__ repl_base,
    uint2* __restrict__ sorted)
{
    int e = blockIdx.x * 256 + threadIdx.x;    // grid covers E exactly
    int d = ei[E_EDGES + e];
    int g = (XCVT_BLOCKS + (e >> 10)) & 7;     // k_pre's blockIdx & 7
    int pos = repl_base[g * N_NODES + d] + (int)rank[e];
    sorted[pos] = wbuf[e];                     // 8B scatter, no dependency
}

// --- K4: gather (f16 x rows) + residual -> v[N][192] f16 --------------------
__global__ __launch_bounds__(256) void k_gather(
    const uint2* __restrict__ sorted, const int* __restrict__ offsets,
    const _Float16* __restrict__ xh, const float* __restrict__ x,
    const float* __restrict__ eps, _Float16* __restrict__ v)
{
    const int n    = blockIdx.x * 4 + (threadIdx.x >> 6);   // grid = N/4 exact
    const int lane = threadIdx.x & 63;

    const int start = offsets[n];
    const int end   = (n + 1 < N_NODES) ? offsets[n + 1] : E_EDGES;

    float a0 = 0.f, a1 = 0.f, a2 = 0.f;
    float b0 = 0.f, b1 = 0.f, b2 = 0.f;
    float c0 = 0.f, c1 = 0.f, c2 = 0.f;
    float d0 = 0.f, d1 = 0.f, d2 = 0.f;

    for (int base = start; base < end; base += 64) {
        const int m = min(64, end - base);
        uint2 rec = make_uint2(0u, 0u);
        if (lane < m) rec = sorted[base + lane];     // coalesced 8B
        int j = 0;
        for (; j + 4 <= m; j += 4) {
            unsigned rxA = (unsigned)__shfl((int)rec.x, j);
            unsigned ryA = (unsigned)__shfl((int)rec.y, j);
            unsigned rxB = (unsigned)__shfl((int)rec.x, j + 1);
            unsigned ryB = (unsigned)__shfl((int)rec.y, j + 1);
            unsigned rxC = (unsigned)__shfl((int)rec.x, j + 2);
            unsigned ryC = (unsigned)__shfl((int)rec.y, j + 2);
            unsigned rxD = (unsigned)__shfl((int)rec.x, j + 3);
            unsigned ryD = (unsigned)__shfl((int)rec.y, j + 3);
            float xA = (float)xh[(size_t)(rxA & 0xFFFFu) * D_FEAT + lane];
            float xB = (float)xh[(size_t)(rxB & 0xFFFFu) * D_FEAT + lane];
            float xC = (float)xh[(size_t)(rxC & 0xFFFFu) * D_FEAT + lane];
            float xD = (float)xh[(size_t)(rxD & 0xFFFFu) * D_FEAT + lane];
            a0 = fmaf(h2f_bits(rxA >> 16),     xA, a0);
            a1 = fmaf(h2f_bits(ryA & 0xFFFFu), xA, a1);
            a2 = fmaf(h2f_bits(ryA >> 16),     xA, a2);
            b0 = fmaf(h2f_bits(rxB >> 16),     xB, b0);
            b1 = fmaf(h2f_bits(ryB & 0xFFFFu), xB, b1);
            b2 = fmaf(h2f_bits(ryB >> 16),     xB, b2);
            c0 = fmaf(h2f_bits(rxC >> 16),     xC, c0);
            c1 = fmaf(h2f_bits(ryC & 0xFFFFu), xC, c1);
            c2 = fmaf(h2f_bits(ryC >> 16),     xC, c2);
            d0 = fmaf(h2f_bits(rxD >> 16),     xD, d0);
            d1 = fmaf(h2f_bits(ryD & 0xFFFFu), xD, d1);
            d2 = fmaf(h2f_bits(ryD >> 16),     xD, d2);
        }
        for (; j < m; ++j) {
            unsigned rx0 = (unsigned)__shfl((int)rec.x, j);
            unsigned ry0 = (unsigned)__shfl((int)rec.y, j);
            float xa = (float)xh[(size_t)(rx0 & 0xFFFFu) * D_FEAT + lane];
            a0 = fmaf(h2f_bits(rx0 >> 16),     xa, a0);
            a1 = fmaf(h2f_bits(ry0 & 0xFFFFu), xa, a1);
            a2 = fmaf(h2f_bits(ry0 >> 16),     xa, a2);
        }
    }
    a0 += b0 + c0 + d0;
    a1 += b1 + c1 + d1;
    a2 += b2 + c2 + d2;

    float xn = x[(size_t)n * D_FEAT + lane];
    _Float16* vr = v + (size_t)n * CD;
    vr[lane]       = (_Float16)(a0 + (1.f + eps[0]) * xn);
    vr[64 + lane]  = (_Float16)(a1 + (1.f + eps[1]) * xn);
    vr[128 + lane] = (_Float16)(a2 + (1.f + eps[2]) * xn);
}

// --- K5: MLP1(lrelu) + MLP2 via f16 MFMA ------------------------------------
__global__ __launch_bounds__(256) void k_mlp(
    const _Float16* __restrict__ v,
    const float* __restrict__ nw1, const float* __restrict__ nb1,
    const float* __restrict__ nw2, const float* __restrict__ nb2,
    float* __restrict__ out)
{
    __shared__ _Float16 vtile[16][CD + 8];     // stride 400B (16B mult)
    __shared__ _Float16 htile[16][OUT_F + 8];  // stride 272B (16B mult)

    const int tid  = threadIdx.x;
    const int lane = tid & 63;
    const int wid  = tid >> 6;
    const int arow = lane & 15;
    const int kg   = lane >> 4;
    const int o0   = wid * 32;

    half8 w1f[6][2], w2f[4][2];
#pragma unroll
    for (int kk = 0; kk < 6; ++kk)
#pragma unroll
        for (int nt = 0; nt < 2; ++nt) {
            half8 f;
            int colb = o0 + nt * 16 + arow;
            int kb = kk * 32 + kg * 8;
#pragma unroll
            for (int j = 0; j < 8; ++j)
                f[j] = (_Float16)nw1[(size_t)(kb + j) * OUT_F + colb];
            w1f[kk][nt] = f;
        }
#pragma unroll
    for (int kk = 0; kk < 4; ++kk)
#pragma unroll
        for (int nt = 0; nt < 2; ++nt) {
            half8 f;
            int colb = o0 + nt * 16 + arow;
            int kb = kk * 32 + kg * 8;
#pragma unroll
            for (int j = 0; j < 8; ++j)
                f[j] = (_Float16)nw2[(size_t)(kb + j) * OUT_F + colb];
            w2f[kk][nt] = f;
        }

    const float b1a = nb1[o0 + arow],      b1b = nb1[o0 + 16 + arow];
    const float b2a = nb2[o0 + arow],      b2b = nb2[o0 + 16 + arow];

    for (int t = blockIdx.x; t < NTILES; t += gridDim.x) {
        const int nb16 = t * 16;
        __syncthreads();

        for (int i = tid; i < 16 * (CD / 8); i += 256) {    // 384 chunks
            int row = i / (CD / 8), c8 = i % (CD / 8);
            *(half8*)&vtile[row][c8 * 8] =
                *(const half8*)(v + (size_t)(nb16 + row) * CD + c8 * 8);
        }
        __syncthreads();

        f32x4 acc0 = {0.f, 0.f, 0.f, 0.f}, acc1 = {0.f, 0.f, 0.f, 0.f};
#pragma unroll
        for (int kk = 0; kk < 6; ++kk) {
            half8 a = *(const half8*)&vtile[arow][kk * 32 + kg * 8];
            acc0 = __builtin_amdgcn_mfma_f32_16x16x32_f16(a, w1f[kk][0], acc0, 0, 0, 0);
            acc1 = __builtin_amdgcn_mfma_f32_16x16x32_f16(a, w1f[kk][1], acc1, 0, 0, 0);
        }
#pragma unroll
        for (int r = 0; r < 4; ++r) {
            int hr = kg * 4 + r;
            htile[hr][o0 + arow]      = (_Float16)lrelu(acc0[r] + b1a);
            htile[hr][o0 + 16 + arow] = (_Float16)lrelu(acc1[r] + b1b);
        }
        __syncthreads();

        f32x4 c0 = {0.f, 0.f, 0.f, 0.f}, c1 = {0.f, 0.f, 0.f, 0.f};
#pragma unroll
        for (int kk = 0; kk < 4; ++kk) {
            half8 a = *(const half8*)&htile[arow][kk * 32 + kg * 8];
            c0 = __builtin_amdgcn_mfma_f32_16x16x32_f16(a, w2f[kk][0], c0, 0, 0, 0);
            c1 = __builtin_amdgcn_mfma_f32_16x16x32_f16(a, w2f[kk][1], c1, 0, 0, 0);
        }
#pragma unroll
        for (int r = 0; r < 4; ++r) {
            size_t n = (size_t)(nb16 + kg * 4 + r);
            out[n * OUT_F + o0 + arow]      = c0[r] + b2a;
            out[n * OUT_F + o0 + 16 + arow] = c1[r] + b2b;
        }
    }
}

extern "C" void kernel_launch(void* const* d_in, const int* in_sizes, int n_in,
                              void* d_out, int out_size, void* d_ws, size_t ws_size,
                              hipStream_t stream)
{
    const float* x    = (const float*)d_in[0];
    const int*   ei   = (const int*)  d_in[1];
    const float* ea   = (const float*)d_in[2];
    const float* w1   = (const float*)d_in[3];
    const float* b1   = (const float*)d_in[4];
    const float* w2   = (const float*)d_in[5];
    const float* b2   = (const float*)d_in[6];
    const float* eps  = (const float*)d_in[7];
    const float* nw1  = (const float*)d_in[8];
    const float* nb1  = (const float*)d_in[9];
    const float* nw2  = (const float*)d_in[10];
    const float* nb2  = (const float*)d_in[11];
    float* out = (float*)d_out;

    // ws layout (bytes): total ~37.0 MB <= proven 38.4 MB
    char* ws = (char*)d_ws;
    int*            counts8   = (int*)           (ws + 0);          // 1,600,000
    int*            blocksums = (int*)           (ws + 1600000);    // 784
    int*            offsets   = (int*)           (ws + 1604096);    // 200,000
    int*            repl_base = (int*)           (ws + 1804800);    // 1,600,000
    unsigned short* rank      = (unsigned short*)(ws + 3404800);    // 1,600,000
    uint2*          wbuf      = (uint2*)         (ws + 5004800);    // 6,400,000
    uint2*          sorted    = (uint2*)         (ws + 11404800);   // 6,400,000
    _Float16*       v         = (_Float16*)      (ws + 17804800);   // 19,200,000

    // xh lives in d_out (6.4 MB of 25.6 MB); dead before k_mlp overwrites
    // (proven safe in rounds 14/18/19)
    _Float16* xh = (_Float16*)d_out;

    hipMemsetAsync(counts8, 0, NREP * N_NODES * sizeof(int), stream);

    k_pre      <<<XCVT_BLOCKS + EDGE_BLOCKS, 256, 0, stream>>>(
        x, xh, ei, ea, w1, b1, w2, b2, wbuf, rank, counts8);
    k_blocksum <<<NBLK_SCAN,   256, 0, stream>>>(counts8, blocksums);
    k_scanfinal<<<NBLK_SCAN,   256, 0, stream>>>(counts8, blocksums, offsets, repl_base);
    k_scat     <<<SCAT_BLOCKS, 256, 0, stream>>>(ei, rank, wbuf, repl_base, sorted);
    k_gather   <<<N_NODES / 4, 256, 0, stream>>>(sorted, offsets, xh, x, eps, v);
    k_mlp      <<<768,         256, 0, stream>>>(v, nw1, nb1, nw2, nb2, out);
}

// Round 22
// 109.733 us; speedup vs baseline: 1.0723x; 1.0437x over previous
//
#include <hip/hip_runtime.h>
#include <math.h>

#define N_NODES 50000
#define E_EDGES 800000
#define D_FEAT  64
#define C_CH    3
#define H_HID   8
#define OUT_F   128
#define CD      192              // C*D
#define NTILES  (N_NODES / 16)   // 3125 exact
#define NBLK_SCAN ((N_NODES + 255) / 256)   // 196
#define XCVT_BLOCKS (N_NODES * D_FEAT / 4 / 256)   // 3125
#define EDGE_BLOCKS ((E_EDGES + 511) / 512)        // 1563 (2 edges/thread)
#define SCAT_BLOCKS (E_EDGES / 256)                // 3125
#define NREP 8

typedef _Float16 half8 __attribute__((ext_vector_type(8)));
typedef _Float16 half4 __attribute__((ext_vector_type(4)));
typedef float f32x4 __attribute__((ext_vector_type(4)));

__device__ __forceinline__ float lrelu(float v) { return v >= 0.f ? v : 0.01f * v; }

__device__ __forceinline__ unsigned short f2h_bits(float f) {
    _Float16 h = (_Float16)f;
    unsigned short b;
    __builtin_memcpy(&b, &h, 2);
    return b;
}
__device__ __forceinline__ float h2f_bits(unsigned b) {
    unsigned short s = (unsigned short)b;
    _Float16 h;
    __builtin_memcpy(&h, &s, 2);
    return (float)h;
}

__device__ __forceinline__ float edge_mlp(
    float a, const float* __restrict__ w1, const float* __restrict__ b1,
    const float* __restrict__ w2, float b2c, int c)
{
    float s = 0.f;
#pragma unroll
    for (int h = 0; h < H_HID; ++h) {
        float t = fmaf(a, w1[c * H_HID + h], b1[c * H_HID + h]);
        t = (t >= 0.f) ? t : 0.01f * t;               // leaky_relu
        s = fmaf(t, w2[c * H_HID + h], s);
    }
    s += b2c;
    return (s > 0.f) ? s : expm1f(s);                 // elu
}

// --- K1: fused {2-edge/thread MLP + wbuf + XCD-local rank} + {x f32->f16} ---
// EDGE blocks come FIRST in the grid: atomic-stalled edge waves launch
// immediately, and the xcvt stream blocks backfill the CUs behind them,
// hiding atomic-return latency under stream work for the whole kernel.
// chains/CU = occupancy(~24 waves) x 2 chains/thread.
__global__ __launch_bounds__(256) void k_pre(
    const float* __restrict__ x, _Float16* __restrict__ xh,
    const int* __restrict__ ei, const float* __restrict__ ea,
    const float* __restrict__ w1, const float* __restrict__ b1,
    const float* __restrict__ w2, const float* __restrict__ b2,
    uint2* __restrict__ wbuf, unsigned short* __restrict__ rank,
    int* __restrict__ counts8)
{
    if (blockIdx.x >= EDGE_BLOCKS) {
        int i = (blockIdx.x - EDGE_BLOCKS) * 256 + threadIdx.x;
        float4 f = ((const float4*)x)[i];
        half4 h;
        h[0] = (_Float16)f.x; h[1] = (_Float16)f.y;
        h[2] = (_Float16)f.z; h[3] = (_Float16)f.w;
        *(half4*)(xh + (size_t)i * 4) = h;
        return;
    }
    const int g  = blockIdx.x & 7;                 // round-robin XCD id
    const int e0 = blockIdx.x * 512 + threadIdx.x * 2;
    const int* dstp = ei + E_EDGES;
    int* cb = counts8 + g * N_NODES;
    const float b20 = b2[0], b21 = b2[1], b22 = b2[2];

    if (e0 + 1 < E_EDGES) {
        int2   sv = *(const int2*)(ei + e0);
        int2   d  = *(const int2*)(dstp + e0);
        float2 a  = *(const float2*)(ea + e0);

        // 2 independent atomic chains, issued up front
        unsigned r0 = (unsigned)atomicAdd(cb + d.x, 1);
        unsigned r1 = (unsigned)atomicAdd(cb + d.y, 1);

        uint2 rec0, rec1;
        {
            float w0 = edge_mlp(a.x, w1, b1, w2, b20, 0);
            float wA = edge_mlp(a.x, w1, b1, w2, b21, 1);
            float wB = edge_mlp(a.x, w1, b1, w2, b22, 2);
            rec0.x = (unsigned)sv.x | ((unsigned)f2h_bits(w0) << 16);
            rec0.y = (unsigned)f2h_bits(wA) | ((unsigned)f2h_bits(wB) << 16);
        }
        {
            float w0 = edge_mlp(a.y, w1, b1, w2, b20, 0);
            float wA = edge_mlp(a.y, w1, b1, w2, b21, 1);
            float wB = edge_mlp(a.y, w1, b1, w2, b22, 2);
            rec1.x = (unsigned)sv.y | ((unsigned)f2h_bits(w0) << 16);
            rec1.y = (unsigned)f2h_bits(wA) | ((unsigned)f2h_bits(wB) << 16);
        }
        *(uint4*)(wbuf + e0) = make_uint4(rec0.x, rec0.y, rec1.x, rec1.y);
        ushort2 rr;
        rr.x = (unsigned short)r0; rr.y = (unsigned short)r1;
        *(ushort2*)(rank + e0) = rr;
    } else {
#pragma unroll
        for (int j = 0; j < 2; ++j) {
            int e = e0 + j;
            if (e < E_EDGES) {
                float aa = ea[e];
                float w0 = edge_mlp(aa, w1, b1, w2, b20, 0);
                float wA = edge_mlp(aa, w1, b1, w2, b21, 1);
                float wB = edge_mlp(aa, w1, b1, w2, b22, 2);
                uint2 r;
                r.x = (unsigned)ei[e] | ((unsigned)f2h_bits(w0) << 16);
                r.y = (unsigned)f2h_bits(wA) | ((unsigned)f2h_bits(wB) << 16);
                wbuf[e] = r;
                rank[e] = (unsigned short)atomicAdd(cb + dstp[e], 1);
            }
        }
    }
}

// --- K2a: per-block sums of total counts (sum over 8 replicas) --------------
__global__ __launch_bounds__(256) void k_blocksum(
    const int* __restrict__ counts8, int* __restrict__ blocksums)
{
    __shared__ int s[256];
    int i = blockIdx.x * 256 + threadIdx.x;
    int t = 0;
    if (i < N_NODES)
#pragma unroll
        for (int g = 0; g < NREP; ++g) t += counts8[g * N_NODES + i];
    s[threadIdx.x] = t;
    __syncthreads();
    for (int off = 128; off >= 1; off >>= 1) {
        if (threadIdx.x < off) s[threadIdx.x] += s[threadIdx.x + off];
        __syncthreads();
    }
    if (threadIdx.x == 0) blocksums[blockIdx.x] = s[0];
}

// --- K2b: scan -> offsets[n] + per-replica bases repl_base[g][n] ------------
__global__ __launch_bounds__(256) void k_scanfinal(
    const int* __restrict__ counts8, const int* __restrict__ blocksums,
    int* __restrict__ offsets, int* __restrict__ repl_base)
{
    __shared__ int bs[256];
    __shared__ int s[256];
    const int tid = threadIdx.x;

    bs[tid] = (tid < NBLK_SCAN) ? blocksums[tid] : 0;
    __syncthreads();
    for (int off = 1; off < 256; off <<= 1) {
        int t = (tid >= off) ? bs[tid - off] : 0;
        __syncthreads();
        bs[tid] += t;
        __syncthreads();
    }
    const int blockoff = (blockIdx.x == 0) ? 0 : bs[blockIdx.x - 1];

    int i = blockIdx.x * 256 + tid;
    int cg[NREP];
    int v = 0;
    if (i < N_NODES) {
#pragma unroll
        for (int g = 0; g < NREP; ++g) {
            cg[g] = counts8[g * N_NODES + i];
            v += cg[g];
        }
    }
    s[tid] = v;
    __syncthreads();
    for (int off = 1; off < 256; off <<= 1) {
        int t = (tid >= off) ? s[tid - off] : 0;
        __syncthreads();
        s[tid] += t;
        __syncthreads();
    }
    if (i < N_NODES) {
        int excl = s[tid] - v + blockoff;      // exclusive global offset
        offsets[i] = excl;
        int run = excl;
#pragma unroll
        for (int g = 0; g < NREP; ++g) {
            repl_base[g * N_NODES + i] = run;
            run += cg[g];
        }
    }
}

// --- K3: rank-based scatter — NO atomics, 1 edge/thread ---------------------
// pos = repl_base[g(e)][dst] + rank[e]; g(e) = k_pre edge-block idx & 7
// = (e>>9)&7 (512 edges per edge block, edge blocks first in grid).
__global__ __launch_bounds__(256) void k_scat(
    const int* __restrict__ ei, const unsigned short* __restrict__ rank,
    const uint2* __restrict__ wbuf, const int* __restrict__ repl_base,
    uint2* __restrict__ sorted)
{
    int e = blockIdx.x * 256 + threadIdx.x;    // grid covers E exactly
    int d = ei[E_EDGES + e];
    int g = (e >> 9) & 7;                      // k_pre's edge blockIdx & 7
    int pos = repl_base[g * N_NODES + d] + (int)rank[e];
    sorted[pos] = wbuf[e];                     // 8B scatter, no dependency
}

// --- K4: gather (f16 x rows) + residual -> v[N][192] f16 --------------------
__global__ __launch_bounds__(256) void k_gather(
    const uint2* __restrict__ sorted, const int* __restrict__ offsets,
    const _Float16* __restrict__ xh, const float* __restrict__ x,
    const float* __restrict__ eps, _Float16* __restrict__ v)
{
    const int n    = blockIdx.x * 4 + (threadIdx.x >> 6);   // grid = N/4 exact
    const int lane = threadIdx.x & 63;

    const int start = offsets[n];
    const int end   = (n + 1 < N_NODES) ? offsets[n + 1] : E_EDGES;

    float a0 = 0.f, a1 = 0.f, a2 = 0.f;
    float b0 = 0.f, b1 = 0.f, b2 = 0.f;
    float c0 = 0.f, c1 = 0.f, c2 = 0.f;
    float d0 = 0.f, d1 = 0.f, d2 = 0.f;

    for (int base = start; base < end; base += 64) {
        const int m = min(64, end - base);
        uint2 rec = make_uint2(0u, 0u);
        if (lane < m) rec = sorted[base + lane];     // coalesced 8B
        int j = 0;
        for (; j + 4 <= m; j += 4) {
            unsigned rxA = (unsigned)__shfl((int)rec.x, j);
            unsigned ryA = (unsigned)__shfl((int)rec.y, j);
            unsigned rxB = (unsigned)__shfl((int)rec.x, j + 1);
            unsigned ryB = (unsigned)__shfl((int)rec.y, j + 1);
            unsigned rxC = (unsigned)__shfl((int)rec.x, j + 2);
            unsigned ryC = (unsigned)__shfl((int)rec.y, j + 2);
            unsigned rxD = (unsigned)__shfl((int)rec.x, j + 3);
            unsigned ryD = (unsigned)__shfl((int)rec.y, j + 3);
            float xA = (float)xh[(size_t)(rxA & 0xFFFFu) * D_FEAT + lane];
            float xB = (float)xh[(size_t)(rxB & 0xFFFFu) * D_FEAT + lane];
            float xC = (float)xh[(size_t)(rxC & 0xFFFFu) * D_FEAT + lane];
            float xD = (float)xh[(size_t)(rxD & 0xFFFFu) * D_FEAT + lane];
            a0 = fmaf(h2f_bits(rxA >> 16),     xA, a0);
            a1 = fmaf(h2f_bits(ryA & 0xFFFFu), xA, a1);
            a2 = fmaf(h2f_bits(ryA >> 16),     xA, a2);
            b0 = fmaf(h2f_bits(rxB >> 16),     xB, b0);
            b1 = fmaf(h2f_bits(ryB & 0xFFFFu), xB, b1);
            b2 = fmaf(h2f_bits(ryB >> 16),     xB, b2);
            c0 = fmaf(h2f_bits(rxC >> 16),     xC, c0);
            c1 = fmaf(h2f_bits(ryC & 0xFFFFu), xC, c1);
            c2 = fmaf(h2f_bits(ryC >> 16),     xC, c2);
            d0 = fmaf(h2f_bits(rxD >> 16),     xD, d0);
            d1 = fmaf(h2f_bits(ryD & 0xFFFFu), xD, d1);
            d2 = fmaf(h2f_bits(ryD >> 16),     xD, d2);
        }
        for (; j < m; ++j) {
            unsigned rx0 = (unsigned)__shfl((int)rec.x, j);
            unsigned ry0 = (unsigned)__shfl((int)rec.y, j);
            float xa = (float)xh[(size_t)(rx0 & 0xFFFFu) * D_FEAT + lane];
            a0 = fmaf(h2f_bits(rx0 >> 16),     xa, a0);
            a1 = fmaf(h2f_bits(ry0 & 0xFFFFu), xa, a1);
            a2 = fmaf(h2f_bits(ry0 >> 16),     xa, a2);
        }
    }
    a0 += b0 + c0 + d0;
    a1 += b1 + c1 + d1;
    a2 += b2 + c2 + d2;

    float xn = x[(size_t)n * D_FEAT + lane];
    _Float16* vr = v + (size_t)n * CD;
    vr[lane]       = (_Float16)(a0 + (1.f + eps[0]) * xn);
    vr[64 + lane]  = (_Float16)(a1 + (1.f + eps[1]) * xn);
    vr[128 + lane] = (_Float16)(a2 + (1.f + eps[2]) * xn);
}

// --- K5: MLP1(lrelu) + MLP2 via f16 MFMA ------------------------------------
__global__ __launch_bounds__(256) void k_mlp(
    const _Float16* __restrict__ v,
    const float* __restrict__ nw1, const float* __restrict__ nb1,
    const float* __restrict__ nw2, const float* __restrict__ nb2,
    float* __restrict__ out)
{
    __shared__ _Float16 vtile[16][CD + 8];     // stride 400B (16B mult)
    __shared__ _Float16 htile[16][OUT_F + 8];  // stride 272B (16B mult)

    const int tid  = threadIdx.x;
    const int lane = tid & 63;
    const int wid  = tid >> 6;
    const int arow = lane & 15;
    const int kg   = lane >> 4;
    const int o0   = wid * 32;

    half8 w1f[6][2], w2f[4][2];
#pragma unroll
    for (int kk = 0; kk < 6; ++kk)
#pragma unroll
        for (int nt = 0; nt < 2; ++nt) {
            half8 f;
            int colb = o0 + nt * 16 + arow;
            int kb = kk * 32 + kg * 8;
#pragma unroll
            for (int j = 0; j < 8; ++j)
                f[j] = (_Float16)nw1[(size_t)(kb + j) * OUT_F + colb];
            w1f[kk][nt] = f;
        }
#pragma unroll
    for (int kk = 0; kk < 4; ++kk)
#pragma unroll
        for (int nt = 0; nt < 2; ++nt) {
            half8 f;
            int colb = o0 + nt * 16 + arow;
            int kb = kk * 32 + kg * 8;
#pragma unroll
            for (int j = 0; j < 8; ++j)
                f[j] = (_Float16)nw2[(size_t)(kb + j) * OUT_F + colb];
            w2f[kk][nt] = f;
        }

    const float b1a = nb1[o0 + arow],      b1b = nb1[o0 + 16 + arow];
    const float b2a = nb2[o0 + arow],      b2b = nb2[o0 + 16 + arow];

    for (int t = blockIdx.x; t < NTILES; t += gridDim.x) {
        const int nb16 = t * 16;
        __syncthreads();

        for (int i = tid; i < 16 * (CD / 8); i += 256) {    // 384 chunks
            int row = i / (CD / 8), c8 = i % (CD / 8);
            *(half8*)&vtile[row][c8 * 8] =
                *(const half8*)(v + (size_t)(nb16 + row) * CD + c8 * 8);
        }
        __syncthreads();

        f32x4 acc0 = {0.f, 0.f, 0.f, 0.f}, acc1 = {0.f, 0.f, 0.f, 0.f};
#pragma unroll
        for (int kk = 0; kk < 6; ++kk) {
            half8 a = *(const half8*)&vtile[arow][kk * 32 + kg * 8];
            acc0 = __builtin_amdgcn_mfma_f32_16x16x32_f16(a, w1f[kk][0], acc0, 0, 0, 0);
            acc1 = __builtin_amdgcn_mfma_f32_16x16x32_f16(a, w1f[kk][1], acc1, 0, 0, 0);
        }
#pragma unroll
        for (int r = 0; r < 4; ++r) {
            int hr = kg * 4 + r;
            htile[hr][o0 + arow]      = (_Float16)lrelu(acc0[r] + b1a);
            htile[hr][o0 + 16 + arow] = (_Float16)lrelu(acc1[r] + b1b);
        }
        __syncthreads();

        f32x4 c0 = {0.f, 0.f, 0.f, 0.f}, c1 = {0.f, 0.f, 0.f, 0.f};
#pragma unroll
        for (int kk = 0; kk < 4; ++kk) {
            half8 a = *(const half8*)&htile[arow][kk * 32 + kg * 8];
            c0 = __builtin_amdgcn_mfma_f32_16x16x32_f16(a, w2f[kk][0], c0, 0, 0, 0);
            c1 = __builtin_amdgcn_mfma_f32_16x16x32_f16(a, w2f[kk][1], c1, 0, 0, 0);
        }
#pragma unroll
        for (int r = 0; r < 4; ++r) {
            size_t n = (size_t)(nb16 + kg * 4 + r);
            out[n * OUT_F + o0 + arow]      = c0[r] + b2a;
            out[n * OUT_F + o0 + 16 + arow] = c1[r] + b2b;
        }
    }
}

extern "C" void kernel_launch(void* const* d_in, const int* in_sizes, int n_in,
                              void* d_out, int out_size, void* d_ws, size_t ws_size,
                              hipStream_t stream)
{
    const float* x    = (const float*)d_in[0];
    const int*   ei   = (const int*)  d_in[1];
    const float* ea   = (const float*)d_in[2];
    const float* w1   = (const float*)d_in[3];
    const float* b1   = (const float*)d_in[4];
    const float* w2   = (const float*)d_in[5];
    const float* b2   = (const float*)d_in[6];
    const float* eps  = (const float*)d_in[7];
    const float* nw1  = (const float*)d_in[8];
    const float* nb1  = (const float*)d_in[9];
    const float* nw2  = (const float*)d_in[10];
    const float* nb2  = (const float*)d_in[11];
    float* out = (float*)d_out;

    // ws layout (bytes): total ~37.0 MB <= proven 38.4 MB
    char* ws = (char*)d_ws;
    int*            counts8   = (int*)           (ws + 0);          // 1,600,000
    int*            blocksums = (int*)           (ws + 1600000);    // 784
    int*            offsets   = (int*)           (ws + 1604096);    // 200,000
    int*            repl_base = (int*)           (ws + 1804800);    // 1,600,000
    unsigned short* rank      = (unsigned short*)(ws + 3404800);    // 1,600,000
    uint2*          wbuf      = (uint2*)         (ws + 5004800);    // 6,400,000
    uint2*          sorted    = (uint2*)         (ws + 11404800);   // 6,400,000
    _Float16*       v         = (_Float16*)      (ws + 17804800);   // 19,200,000

    // xh lives in d_out (6.4 MB of 25.6 MB); dead before k_mlp overwrites
    // (proven safe in rounds 14/18/19)
    _Float16* xh = (_Float16*)d_out;

    hipMemsetAsync(counts8, 0, NREP * N_NODES * sizeof(int), stream);

    k_pre      <<<EDGE_BLOCKS + XCVT_BLOCKS, 256, 0, stream>>>(
        x, xh, ei, ea, w1, b1, w2, b2, wbuf, rank, counts8);
    k_blocksum <<<NBLK_SCAN,   256, 0, stream>>>(counts8, blocksums);
    k_scanfinal<<<NBLK_SCAN,   256, 0, stream>>>(counts8, blocksums, offsets, repl_base);
    k_scat     <<<SCAT_BLOCKS, 256, 0, stream>>>(ei, rank, wbuf, repl_base, sorted);
    k_gather   <<<N_NODES / 4, 256, 0, stream>>>(sorted, offsets, xh, x, eps, v);
    k_mlp      <<<768,         256, 0, stream>>>(v, nw1, nb1, nw2, nb2, out);
}

// Round 23
// 108.984 us; speedup vs baseline: 1.0797x; 1.0069x over previous
//
#include <hip/hip_runtime.h>
#include <math.h>

#define N_NODES 50000
#define E_EDGES 800000
#define D_FEAT  64
#define C_CH    3
#define H_HID   8
#define OUT_F   128
#define CD      192              // C*D
#define NTILES  (N_NODES / 16)   // 3125 exact
#define NBLK_SCAN ((N_NODES + 255) / 256)   // 196
#define XCVT_BLOCKS (N_NODES * D_FEAT / 4 / 256)   // 3125
#define EDGE_BLOCKS ((E_EDGES + 511) / 512)        // 1563 (2 edges/thread)
#define SCAT_BLOCKS ((E_EDGES + 1023) / 1024)      // 782 (4 edges/thread)
#define NREP 8

typedef _Float16 half8 __attribute__((ext_vector_type(8)));
typedef _Float16 half4 __attribute__((ext_vector_type(4)));
typedef float f32x4 __attribute__((ext_vector_type(4)));

__device__ __forceinline__ float lrelu(float v) { return v >= 0.f ? v : 0.01f * v; }

__device__ __forceinline__ unsigned short f2h_bits(float f) {
    _Float16 h = (_Float16)f;
    unsigned short b;
    __builtin_memcpy(&b, &h, 2);
    return b;
}
__device__ __forceinline__ float h2f_bits(unsigned b) {
    unsigned short s = (unsigned short)b;
    _Float16 h;
    __builtin_memcpy(&h, &s, 2);
    return (float)h;
}

__device__ __forceinline__ float edge_mlp(
    float a, const float* __restrict__ w1, const float* __restrict__ b1,
    const float* __restrict__ w2, float b2c, int c)
{
    float s = 0.f;
#pragma unroll
    for (int h = 0; h < H_HID; ++h) {
        float t = fmaf(a, w1[c * H_HID + h], b1[c * H_HID + h]);
        t = (t >= 0.f) ? t : 0.01f * t;               // leaky_relu
        s = fmaf(t, w2[c * H_HID + h], s);
    }
    s += b2c;
    return (s > 0.f) ? s : expm1f(s);                 // elu
}

// --- K1: fused {2-edge/thread MLP + wbuf + XCD-local rank} + {x f32->f16} ---
// EDGE blocks first: atomic-stalled edge waves launch immediately; xcvt
// stream blocks backfill the CUs behind them, hiding atomic-return latency.
__global__ __launch_bounds__(256) void k_pre(
    const float* __restrict__ x, _Float16* __restrict__ xh,
    const int* __restrict__ ei, const float* __restrict__ ea,
    const float* __restrict__ w1, const float* __restrict__ b1,
    const float* __restrict__ w2, const float* __restrict__ b2,
    uint2* __restrict__ wbuf, unsigned short* __restrict__ rank,
    int* __restrict__ counts8)
{
    if (blockIdx.x >= EDGE_BLOCKS) {
        int i = (blockIdx.x - EDGE_BLOCKS) * 256 + threadIdx.x;
        float4 f = ((const float4*)x)[i];
        half4 h;
        h[0] = (_Float16)f.x; h[1] = (_Float16)f.y;
        h[2] = (_Float16)f.z; h[3] = (_Float16)f.w;
        *(half4*)(xh + (size_t)i * 4) = h;
        return;
    }
    const int g  = blockIdx.x & 7;                 // round-robin XCD id
    const int e0 = blockIdx.x * 512 + threadIdx.x * 2;
    const int* dstp = ei + E_EDGES;
    int* cb = counts8 + g * N_NODES;
    const float b20 = b2[0], b21 = b2[1], b22 = b2[2];

    if (e0 + 1 < E_EDGES) {
        int2   sv = *(const int2*)(ei + e0);
        int2   d  = *(const int2*)(dstp + e0);
        float2 a  = *(const float2*)(ea + e0);

        unsigned r0 = (unsigned)atomicAdd(cb + d.x, 1);
        unsigned r1 = (unsigned)atomicAdd(cb + d.y, 1);

        uint2 rec0, rec1;
        {
            float w0 = edge_mlp(a.x, w1, b1, w2, b20, 0);
            float wA = edge_mlp(a.x, w1, b1, w2, b21, 1);
            float wB = edge_mlp(a.x, w1, b1, w2, b22, 2);
            rec0.x = (unsigned)sv.x | ((unsigned)f2h_bits(w0) << 16);
            rec0.y = (unsigned)f2h_bits(wA) | ((unsigned)f2h_bits(wB) << 16);
        }
        {
            float w0 = edge_mlp(a.y, w1, b1, w2, b20, 0);
            float wA = edge_mlp(a.y, w1, b1, w2, b21, 1);
            float wB = edge_mlp(a.y, w1, b1, w2, b22, 2);
            rec1.x = (unsigned)sv.y | ((unsigned)f2h_bits(w0) << 16);
            rec1.y = (unsigned)f2h_bits(wA) | ((unsigned)f2h_bits(wB) << 16);
        }
        *(uint4*)(wbuf + e0) = make_uint4(rec0.x, rec0.y, rec1.x, rec1.y);
        ushort2 rr;
        rr.x = (unsigned short)r0; rr.y = (unsigned short)r1;
        *(ushort2*)(rank + e0) = rr;
    } else {
#pragma unroll
        for (int j = 0; j < 2; ++j) {
            int e = e0 + j;
            if (e < E_EDGES) {
                float aa = ea[e];
                float w0 = edge_mlp(aa, w1, b1, w2, b20, 0);
                float wA = edge_mlp(aa, w1, b1, w2, b21, 1);
                float wB = edge_mlp(aa, w1, b1, w2, b22, 2);
                uint2 r;
                r.x = (unsigned)ei[e] | ((unsigned)f2h_bits(w0) << 16);
                r.y = (unsigned)f2h_bits(wA) | ((unsigned)f2h_bits(wB) << 16);
                wbuf[e] = r;
                rank[e] = (unsigned short)atomicAdd(cb + dstp[e], 1);
            }
        }
    }
}

// --- K2a: per-block sums of total counts (sum over 8 replicas) --------------
__global__ __launch_bounds__(256) void k_blocksum(
    const int* __restrict__ counts8, int* __restrict__ blocksums)
{
    __shared__ int s[256];
    int i = blockIdx.x * 256 + threadIdx.x;
    int t = 0;
    if (i < N_NODES)
#pragma unroll
        for (int g = 0; g < NREP; ++g) t += counts8[g * N_NODES + i];
    s[threadIdx.x] = t;
    __syncthreads();
    for (int off = 128; off >= 1; off >>= 1) {
        if (threadIdx.x < off) s[threadIdx.x] += s[threadIdx.x + off];
        __syncthreads();
    }
    if (threadIdx.x == 0) blocksums[blockIdx.x] = s[0];
}

// --- K2b: scan -> offsets[n] + per-replica bases repl_base[g][n] ------------
__global__ __launch_bounds__(256) void k_scanfinal(
    const int* __restrict__ counts8, const int* __restrict__ blocksums,
    int* __restrict__ offsets, int* __restrict__ repl_base)
{
    __shared__ int bs[256];
    __shared__ int s[256];
    const int tid = threadIdx.x;

    bs[tid] = (tid < NBLK_SCAN) ? blocksums[tid] : 0;
    __syncthreads();
    for (int off = 1; off < 256; off <<= 1) {
        int t = (tid >= off) ? bs[tid - off] : 0;
        __syncthreads();
        bs[tid] += t;
        __syncthreads();
    }
    const int blockoff = (blockIdx.x == 0) ? 0 : bs[blockIdx.x - 1];

    int i = blockIdx.x * 256 + tid;
    int cg[NREP];
    int v = 0;
    if (i < N_NODES) {
#pragma unroll
        for (int g = 0; g < NREP; ++g) {
            cg[g] = counts8[g * N_NODES + i];
            v += cg[g];
        }
    }
    s[tid] = v;
    __syncthreads();
    for (int off = 1; off < 256; off <<= 1) {
        int t = (tid >= off) ? s[tid - off] : 0;
        __syncthreads();
        s[tid] += t;
        __syncthreads();
    }
    if (i < N_NODES) {
        int excl = s[tid] - v + blockoff;      // exclusive global offset
        offsets[i] = excl;
        int run = excl;
#pragma unroll
        for (int g = 0; g < NREP; ++g) {
            repl_base[g * N_NODES + i] = run;
            run += cg[g];
        }
    }
}

// --- K3: rank-based scatter — NO atomics, 4 edges/thread --------------------
// pos = repl_base[g(e)][dst] + rank[e]; g(e) = (e>>9)&7 (k_pre edge block).
__global__ __launch_bounds__(256) void k_scat(
    const int* __restrict__ ei, const unsigned short* __restrict__ rank,
    const uint2* __restrict__ wbuf, const int* __restrict__ repl_base,
    uint2* __restrict__ sorted)
{
    int e0 = blockIdx.x * 1024 + threadIdx.x * 4;
    const int* dstp = ei + E_EDGES;

    if (e0 + 3 < E_EDGES) {
        int4    d  = *(const int4*)(dstp + e0);
        ushort4 rr = *(const ushort4*)(rank + e0);
        uint4   wA = *(const uint4*)(wbuf + e0);
        uint4   wB = *(const uint4*)(wbuf + e0 + 2);
        int g0 = ((e0    ) >> 9) & 7;
        int g1 = ((e0 + 1) >> 9) & 7;
        int g2 = ((e0 + 2) >> 9) & 7;
        int g3 = ((e0 + 3) >> 9) & 7;
        sorted[repl_base[g0 * N_NODES + d.x] + (int)rr.x] = make_uint2(wA.x, wA.y);
        sorted[repl_base[g1 * N_NODES + d.y] + (int)rr.y] = make_uint2(wA.z, wA.w);
        sorted[repl_base[g2 * N_NODES + d.z] + (int)rr.z] = make_uint2(wB.x, wB.y);
        sorted[repl_base[g3 * N_NODES + d.w] + (int)rr.w] = make_uint2(wB.z, wB.w);
    } else {
#pragma unroll
        for (int j = 0; j < 4; ++j) {
            int e = e0 + j;
            if (e < E_EDGES) {
                int d = dstp[e];
                int g = (e >> 9) & 7;
                sorted[repl_base[g * N_NODES + d] + (int)rank[e]] = wbuf[e];
            }
        }
    }
}

// --- K4: gather (f16 x rows) + residual (from xh) -> v[N][192] f16 ----------
__global__ __launch_bounds__(256) void k_gather(
    const uint2* __restrict__ sorted, const int* __restrict__ offsets,
    const _Float16* __restrict__ xh, const float* __restrict__ eps,
    _Float16* __restrict__ v)
{
    const int n    = blockIdx.x * 4 + (threadIdx.x >> 6);   // grid = N/4 exact
    const int lane = threadIdx.x & 63;

    const int start = offsets[n];
    const int end   = (n + 1 < N_NODES) ? offsets[n + 1] : E_EDGES;

    // residual load hoisted: independent of the edge chain
    float xn = (float)xh[(size_t)n * D_FEAT + lane];

    float a0 = 0.f, a1 = 0.f, a2 = 0.f;
    float b0 = 0.f, b1 = 0.f, b2 = 0.f;
    float c0 = 0.f, c1 = 0.f, c2 = 0.f;
    float d0 = 0.f, d1 = 0.f, d2 = 0.f;

    for (int base = start; base < end; base += 64) {
        const int m = min(64, end - base);
        uint2 rec = make_uint2(0u, 0u);
        if (lane < m) rec = sorted[base + lane];     // coalesced 8B
        int j = 0;
        for (; j + 4 <= m; j += 4) {
            unsigned rxA = (unsigned)__shfl((int)rec.x, j);
            unsigned ryA = (unsigned)__shfl((int)rec.y, j);
            unsigned rxB = (unsigned)__shfl((int)rec.x, j + 1);
            unsigned ryB = (unsigned)__shfl((int)rec.y, j + 1);
            unsigned rxC = (unsigned)__shfl((int)rec.x, j + 2);
            unsigned ryC = (unsigned)__shfl((int)rec.y, j + 2);
            unsigned rxD = (unsigned)__shfl((int)rec.x, j + 3);
            unsigned ryD = (unsigned)__shfl((int)rec.y, j + 3);
            float xA = (float)xh[(size_t)(rxA & 0xFFFFu) * D_FEAT + lane];
            float xB = (float)xh[(size_t)(rxB & 0xFFFFu) * D_FEAT + lane];
            float xC = (float)xh[(size_t)(rxC & 0xFFFFu) * D_FEAT + lane];
            float xD = (float)xh[(size_t)(rxD & 0xFFFFu) * D_FEAT + lane];
            a0 = fmaf(h2f_bits(rxA >> 16),     xA, a0);
            a1 = fmaf(h2f_bits(ryA & 0xFFFFu), xA, a1);
            a2 = fmaf(h2f_bits(ryA >> 16),     xA, a2);
            b0 = fmaf(h2f_bits(rxB >> 16),     xB, b0);
            b1 = fmaf(h2f_bits(ryB & 0xFFFFu), xB, b1);
            b2 = fmaf(h2f_bits(ryB >> 16),     xB, b2);
            c0 = fmaf(h2f_bits(rxC >> 16),     xC, c0);
            c1 = fmaf(h2f_bits(ryC & 0xFFFFu), xC, c1);
            c2 = fmaf(h2f_bits(ryC >> 16),     xC, c2);
            d0 = fmaf(h2f_bits(rxD >> 16),     xD, d0);
            d1 = fmaf(h2f_bits(ryD & 0xFFFFu), xD, d1);
            d2 = fmaf(h2f_bits(ryD >> 16),     xD, d2);
        }
        for (; j < m; ++j) {
            unsigned rx0 = (unsigned)__shfl((int)rec.x, j);
            unsigned ry0 = (unsigned)__shfl((int)rec.y, j);
            float xa = (float)xh[(size_t)(rx0 & 0xFFFFu) * D_FEAT + lane];
            a0 = fmaf(h2f_bits(rx0 >> 16),     xa, a0);
            a1 = fmaf(h2f_bits(ry0 & 0xFFFFu), xa, a1);
            a2 = fmaf(h2f_bits(ry0 >> 16),     xa, a2);
        }
    }
    a0 += b0 + c0 + d0;
    a1 += b1 + c1 + d1;
    a2 += b2 + c2 + d2;

    _Float16* vr = v + (size_t)n * CD;
    vr[lane]       = (_Float16)(a0 + (1.f + eps[0]) * xn);
    vr[64 + lane]  = (_Float16)(a1 + (1.f + eps[1]) * xn);
    vr[128 + lane] = (_Float16)(a2 + (1.f + eps[2]) * xn);
}

// --- K5: MLP1(lrelu) + MLP2 via f16 MFMA ------------------------------------
__global__ __launch_bounds__(256) void k_mlp(
    const _Float16* __restrict__ v,
    const float* __restrict__ nw1, const float* __restrict__ nb1,
    const float* __restrict__ nw2, const float* __restrict__ nb2,
    float* __restrict__ out)
{
    __shared__ _Float16 vtile[16][CD + 8];     // stride 400B (16B mult)
    __shared__ _Float16 htile[16][OUT_F + 8];  // stride 272B (16B mult)

    const int tid  = threadIdx.x;
    const int lane = tid & 63;
    const int wid  = tid >> 6;
    const int arow = lane & 15;
    const int kg   = lane >> 4;
    const int o0   = wid * 32;

    half8 w1f[6][2], w2f[4][2];
#pragma unroll
    for (int kk = 0; kk < 6; ++kk)
#pragma unroll
        for (int nt = 0; nt < 2; ++nt) {
            half8 f;
            int colb = o0 + nt * 16 + arow;
            int kb = kk * 32 + kg * 8;
#pragma unroll
            for (int j = 0; j < 8; ++j)
                f[j] = (_Float16)nw1[(size_t)(kb + j) * OUT_F + colb];
            w1f[kk][nt] = f;
        }
#pragma unroll
    for (int kk = 0; kk < 4; ++kk)
#pragma unroll
        for (int nt = 0; nt < 2; ++nt) {
            half8 f;
            int colb = o0 + nt * 16 + arow;
            int kb = kk * 32 + kg * 8;
#pragma unroll
            for (int j = 0; j < 8; ++j)
                f[j] = (_Float16)nw2[(size_t)(kb + j) * OUT_F + colb];
            w2f[kk][nt] = f;
        }

    const float b1a = nb1[o0 + arow],      b1b = nb1[o0 + 16 + arow];
    const float b2a = nb2[o0 + arow],      b2b = nb2[o0 + 16 + arow];

    for (int t = blockIdx.x; t < NTILES; t += gridDim.x) {
        const int nb16 = t * 16;
        __syncthreads();

        for (int i = tid; i < 16 * (CD / 8); i += 256) {    // 384 chunks
            int row = i / (CD / 8), c8 = i % (CD / 8);
            *(half8*)&vtile[row][c8 * 8] =
                *(const half8*)(v + (size_t)(nb16 + row) * CD + c8 * 8);
        }
        __syncthreads();

        f32x4 acc0 = {0.f, 0.f, 0.f, 0.f}, acc1 = {0.f, 0.f, 0.f, 0.f};
#pragma unroll
        for (int kk = 0; kk < 6; ++kk) {
            half8 a = *(const half8*)&vtile[arow][kk * 32 + kg * 8];
            acc0 = __builtin_amdgcn_mfma_f32_16x16x32_f16(a, w1f[kk][0], acc0, 0, 0, 0);
            acc1 = __builtin_amdgcn_mfma_f32_16x16x32_f16(a, w1f[kk][1], acc1, 0, 0, 0);
        }
#pragma unroll
        for (int r = 0; r < 4; ++r) {
            int hr = kg * 4 + r;
            htile[hr][o0 + arow]      = (_Float16)lrelu(acc0[r] + b1a);
            htile[hr][o0 + 16 + arow] = (_Float16)lrelu(acc1[r] + b1b);
        }
        __syncthreads();

        f32x4 c0 = {0.f, 0.f, 0.f, 0.f}, c1 = {0.f, 0.f, 0.f, 0.f};
#pragma unroll
        for (int kk = 0; kk < 4; ++kk) {
            half8 a = *(const half8*)&htile[arow][kk * 32 + kg * 8];
            c0 = __builtin_amdgcn_mfma_f32_16x16x32_f16(a, w2f[kk][0], c0, 0, 0, 0);
            c1 = __builtin_amdgcn_mfma_f32_16x16x32_f16(a, w2f[kk][1], c1, 0, 0, 0);
        }
#pragma unroll
        for (int r = 0; r < 4; ++r) {
            size_t n = (size_t)(nb16 + kg * 4 + r);
            out[n * OUT_F + o0 + arow]      = c0[r] + b2a;
            out[n * OUT_F + o0 + 16 + arow] = c1[r] + b2b;
        }
    }
}

extern "C" void kernel_launch(void* const* d_in, const int* in_sizes, int n_in,
                              void* d_out, int out_size, void* d_ws, size_t ws_size,
                              hipStream_t stream)
{
    const float* x    = (const float*)d_in[0];
    const int*   ei   = (const int*)  d_in[1];
    const float* ea   = (const float*)d_in[2];
    const float* w1   = (const float*)d_in[3];
    const float* b1   = (const float*)d_in[4];
    const float* w2   = (const float*)d_in[5];
    const float* b2   = (const float*)d_in[6];
    const float* eps  = (const float*)d_in[7];
    const float* nw1  = (const float*)d_in[8];
    const float* nb1  = (const float*)d_in[9];
    const float* nw2  = (const float*)d_in[10];
    const float* nb2  = (const float*)d_in[11];
    float* out = (float*)d_out;

    // ws layout (bytes): total ~37.0 MB <= proven 38.4 MB
    char* ws = (char*)d_ws;
    int*            counts8   = (int*)           (ws + 0);          // 1,600,000
    int*            blocksums = (int*)           (ws + 1600000);    // 784
    int*            offsets   = (int*)           (ws + 1604096);    // 200,000
    int*            repl_base = (int*)           (ws + 1804800);    // 1,600,000
    unsigned short* rank      = (unsigned short*)(ws + 3404800);    // 1,600,000
    uint2*          wbuf      = (uint2*)         (ws + 5004800);    // 6,400,000
    uint2*          sorted    = (uint2*)         (ws + 11404800);   // 6,400,000
    _Float16*       v         = (_Float16*)      (ws + 17804800);   // 19,200,000

    // xh lives in d_out (6.4 MB of 25.6 MB); dead before k_mlp overwrites
    // (proven safe in rounds 14/18/19)
    _Float16* xh = (_Float16*)d_out;

    hipMemsetAsync(counts8, 0, NREP * N_NODES * sizeof(int), stream);

    k_pre      <<<EDGE_BLOCKS + XCVT_BLOCKS, 256, 0, stream>>>(
        x, xh, ei, ea, w1, b1, w2, b2, wbuf, rank, counts8);
    k_blocksum <<<NBLK_SCAN,   256, 0, stream>>>(counts8, blocksums);
    k_scanfinal<<<NBLK_SCAN,   256, 0, stream>>>(counts8, blocksums, offsets, repl_base);
    k_scat     <<<SCAT_BLOCKS, 256, 0, stream>>>(ei, rank, wbuf, repl_base, sorted);
    k_gather   <<<N_NODES / 4, 256, 0, stream>>>(sorted, offsets, xh, eps, v);
    k_mlp      <<<768,         256, 0, stream>>>(v, nw1, nb1, nw2, nb2, out);
}

// Round 24
// 94.163 us; speedup vs baseline: 1.2496x; 1.1574x over previous
//
#include <hip/hip_runtime.h>
#include <math.h>

#define N_NODES 50000
#define E_EDGES 800000
#define D_FEAT  64
#define C_CH    3
#define H_HID   8
#define OUT_F   128
#define CD      192              // C*D
#define NTILES  (N_NODES / 16)   // 3125 exact
#define XCVT_BLOCKS (N_NODES * D_FEAT / 4 / 256)   // 3125
#define EDGEB   ((E_EDGES + 1023) / 1024)          // 782 (4 edges/thread)
#define NBUCK   196              // buckets of 256 nodes (dst>>8)
#define BCAP    5120             // per-bucket capacity (mean 4096, +16 sigma)

typedef _Float16 half8 __attribute__((ext_vector_type(8)));
typedef _Float16 half4 __attribute__((ext_vector_type(4)));
typedef float f32x4 __attribute__((ext_vector_type(4)));

__device__ __forceinline__ float lrelu(float v) { return v >= 0.f ? v : 0.01f * v; }

__device__ __forceinline__ unsigned short f2h_bits(float f) {
    _Float16 h = (_Float16)f;
    unsigned short b;
    __builtin_memcpy(&b, &h, 2);
    return b;
}
__device__ __forceinline__ float h2f_bits(unsigned b) {
    unsigned short s = (unsigned short)b;
    _Float16 h;
    __builtin_memcpy(&h, &s, 2);
    return (float)h;
}

__device__ __forceinline__ float edge_mlp(
    float a, const float* __restrict__ w1, const float* __restrict__ b1,
    const float* __restrict__ w2, float b2c, int c)
{
    float s = 0.f;
#pragma unroll
    for (int h = 0; h < H_HID; ++h) {
        float t = fmaf(a, w1[c * H_HID + h], b1[c * H_HID + h]);
        t = (t >= 0.f) ? t : 0.01f * t;               // leaky_relu
        s = fmaf(t, w2[c * H_HID + h], s);
    }
    s += b2c;
    return (s > 0.f) ? s : expm1f(s);                 // elu
}

// --- K1: {edge MLP + coarse-bucket partition (LDS int hist)} + {x->f16} -----
// NO per-edge global atomics: per-edge rank via native LDS ds_add; ONE global
// cursor atomic per (block,bucket). Edge blocks first; xcvt blocks backfill.
__global__ __launch_bounds__(256) void k_part(
    const float* __restrict__ x, _Float16* __restrict__ xh,
    const int* __restrict__ ei, const float* __restrict__ ea,
    const float* __restrict__ w1, const float* __restrict__ b1,
    const float* __restrict__ w2, const float* __restrict__ b2,
    int* __restrict__ bcnt, uint2* __restrict__ brec,
    unsigned char* __restrict__ bd8)
{
    if (blockIdx.x >= EDGEB) {
        int i = (blockIdx.x - EDGEB) * 256 + threadIdx.x;
        float4 f = ((const float4*)x)[i];
        half4 h;
        h[0] = (_Float16)f.x; h[1] = (_Float16)f.y;
        h[2] = (_Float16)f.z; h[3] = (_Float16)f.w;
        *(half4*)(xh + (size_t)i * 4) = h;
        return;
    }
    __shared__ int hist[256];
    __shared__ int gbase[256];

    const int tid = threadIdx.x;
    const int e0  = blockIdx.x * 1024 + tid * 4;
    const int* dstp = ei + E_EDGES;
    const float b20 = b2[0], b21 = b2[1], b22 = b2[2];

    hist[tid] = 0;
    __syncthreads();

    int   sv[4], de[4];
    float av[4];
    if (e0 + 3 < E_EDGES) {
        int4   s4 = *(const int4*)(ei + e0);
        int4   d4 = *(const int4*)(dstp + e0);
        float4 a4 = *(const float4*)(ea + e0);
        sv[0]=s4.x; sv[1]=s4.y; sv[2]=s4.z; sv[3]=s4.w;
        de[0]=d4.x; de[1]=d4.y; de[2]=d4.z; de[3]=d4.w;
        av[0]=a4.x; av[1]=a4.y; av[2]=a4.z; av[3]=a4.w;
    } else {
#pragma unroll
        for (int j = 0; j < 4; ++j) {
            int e = e0 + j;
            sv[j] = (e < E_EDGES) ? ei[e]   : 0;
            de[j] = (e < E_EDGES) ? dstp[e] : -1;
            av[j] = (e < E_EDGES) ? ea[e]   : 0.f;
        }
    }

    int bk[4], lr[4];
#pragma unroll
    for (int j = 0; j < 4; ++j) {
        if (de[j] >= 0) {
            bk[j] = de[j] >> 8;
            lr[j] = atomicAdd(&hist[bk[j]], 1);   // native LDS int atomic
        } else bk[j] = -1;
    }
    __syncthreads();
    if (tid < NBUCK && hist[tid]) gbase[tid] = atomicAdd(bcnt + tid, hist[tid]);
    __syncthreads();

#pragma unroll
    for (int j = 0; j < 4; ++j) {
        if (bk[j] >= 0) {
            float w0 = edge_mlp(av[j], w1, b1, w2, b20, 0);
            float wA = edge_mlp(av[j], w1, b1, w2, b21, 1);
            float wB = edge_mlp(av[j], w1, b1, w2, b22, 2);
            uint2 r;
            r.x = (unsigned)sv[j] | ((unsigned)f2h_bits(w0) << 16);
            r.y = (unsigned)f2h_bits(wA) | ((unsigned)f2h_bits(wB) << 16);
            int pos = gbase[bk[j]] + lr[j];
            brec[(size_t)bk[j] * BCAP + pos] = r;
            bd8 [(size_t)bk[j] * BCAP + pos] = (unsigned char)(de[j] & 255);
        }
    }
}

// --- K2: per-bucket fine sort (LDS) + DIRECT offsets emission ---------------
// one block per bucket (256 nodes, ~4100 records). All sorting traffic is
// bucket-local; per-node offsets written coalesced — no global scan kernels.
__global__ __launch_bounds__(256) void k_sortb(
    const int* __restrict__ bcnt, const uint2* __restrict__ brec,
    const unsigned char* __restrict__ bd8,
    int* __restrict__ offsets, uint2* __restrict__ sorted)
{
    __shared__ int sc[256];
    __shared__ int nodeh[256];
    __shared__ int pfx[256];
    __shared__ int cursor[256];
    __shared__ unsigned char s8[BCAP];

    const int tid = threadIdx.x;
    const int b   = blockIdx.x;

    // bucket base: redundant inclusive scan of the 196 bucket counts
    sc[tid]    = (tid < NBUCK) ? bcnt[tid] : 0;
    nodeh[tid] = 0;
    __syncthreads();
    for (int off = 1; off < 256; off <<= 1) {
        int t = (tid >= off) ? sc[tid - off] : 0;
        __syncthreads();
        sc[tid] += t;
        __syncthreads();
    }
    const int base = (b == 0) ? 0 : sc[b - 1];
    const int cnt  = bcnt[b];

    // node histogram (LDS int atomics), stash dst-low bytes
    for (int i = tid; i < cnt; i += 256) {
        unsigned char d = bd8[(size_t)b * BCAP + i];
        s8[i] = d;
        atomicAdd(&nodeh[d], 1);
    }
    __syncthreads();

    // exclusive prefix over the 256 node slots
    pfx[tid] = nodeh[tid];
    __syncthreads();
    for (int off = 1; off < 256; off <<= 1) {
        int t = (tid >= off) ? pfx[tid - off] : 0;
        __syncthreads();
        pfx[tid] += t;
        __syncthreads();
    }
    const int excl = pfx[tid] - nodeh[tid];
    cursor[tid] = excl;
    int n = b * 256 + tid;
    if (n < N_NODES) offsets[n] = base + excl;   // coalesced, no scan kernels
    __syncthreads();

    // scatter records to final dst-sorted positions (bucket-local region)
    for (int i = tid; i < cnt; i += 256) {
        uint2 r = brec[(size_t)b * BCAP + i];
        int pos = atomicAdd(&cursor[s8[i]], 1);
        sorted[base + pos] = r;
    }
}

// --- K3: gather (f16 x rows) + residual (from xh) -> v[N][192] f16 ----------
__global__ __launch_bounds__(256) void k_gather(
    const uint2* __restrict__ sorted, const int* __restrict__ offsets,
    const _Float16* __restrict__ xh, const float* __restrict__ eps,
    _Float16* __restrict__ v)
{
    const int n    = blockIdx.x * 4 + (threadIdx.x >> 6);   // grid = N/4 exact
    const int lane = threadIdx.x & 63;

    const int start = offsets[n];
    const int end   = (n + 1 < N_NODES) ? offsets[n + 1] : E_EDGES;

    float xn = (float)xh[(size_t)n * D_FEAT + lane];

    float a0 = 0.f, a1 = 0.f, a2 = 0.f;
    float b0 = 0.f, b1 = 0.f, b2 = 0.f;
    float c0 = 0.f, c1 = 0.f, c2 = 0.f;
    float d0 = 0.f, d1 = 0.f, d2 = 0.f;

    for (int base = start; base < end; base += 64) {
        const int m = min(64, end - base);
        uint2 rec = make_uint2(0u, 0u);
        if (lane < m) rec = sorted[base + lane];     // coalesced 8B
        int j = 0;
        for (; j + 4 <= m; j += 4) {
            unsigned rxA = (unsigned)__shfl((int)rec.x, j);
            unsigned ryA = (unsigned)__shfl((int)rec.y, j);
            unsigned rxB = (unsigned)__shfl((int)rec.x, j + 1);
            unsigned ryB = (unsigned)__shfl((int)rec.y, j + 1);
            unsigned rxC = (unsigned)__shfl((int)rec.x, j + 2);
            unsigned ryC = (unsigned)__shfl((int)rec.y, j + 2);
            unsigned rxD = (unsigned)__shfl((int)rec.x, j + 3);
            unsigned ryD = (unsigned)__shfl((int)rec.y, j + 3);
            float xA = (float)xh[(size_t)(rxA & 0xFFFFu) * D_FEAT + lane];
            float xB = (float)xh[(size_t)(rxB & 0xFFFFu) * D_FEAT + lane];
            float xC = (float)xh[(size_t)(rxC & 0xFFFFu) * D_FEAT + lane];
            float xD = (float)xh[(size_t)(rxD & 0xFFFFu) * D_FEAT + lane];
            a0 = fmaf(h2f_bits(rxA >> 16),     xA, a0);
            a1 = fmaf(h2f_bits(ryA & 0xFFFFu), xA, a1);
            a2 = fmaf(h2f_bits(ryA >> 16),     xA, a2);
            b0 = fmaf(h2f_bits(rxB >> 16),     xB, b0);
            b1 = fmaf(h2f_bits(ryB & 0xFFFFu), xB, b1);
            b2 = fmaf(h2f_bits(ryB >> 16),     xB, b2);
            c0 = fmaf(h2f_bits(rxC >> 16),     xC, c0);
            c1 = fmaf(h2f_bits(ryC & 0xFFFFu), xC, c1);
            c2 = fmaf(h2f_bits(ryC >> 16),     xC, c2);
            d0 = fmaf(h2f_bits(rxD >> 16),     xD, d0);
            d1 = fmaf(h2f_bits(ryD & 0xFFFFu), xD, d1);
            d2 = fmaf(h2f_bits(ryD >> 16),     xD, d2);
        }
        for (; j < m; ++j) {
            unsigned rx0 = (unsigned)__shfl((int)rec.x, j);
            unsigned ry0 = (unsigned)__shfl((int)rec.y, j);
            float xa = (float)xh[(size_t)(rx0 & 0xFFFFu) * D_FEAT + lane];
            a0 = fmaf(h2f_bits(rx0 >> 16),     xa, a0);
            a1 = fmaf(h2f_bits(ry0 & 0xFFFFu), xa, a1);
            a2 = fmaf(h2f_bits(ry0 >> 16),     xa, a2);
        }
    }
    a0 += b0 + c0 + d0;
    a1 += b1 + c1 + d1;
    a2 += b2 + c2 + d2;

    _Float16* vr = v + (size_t)n * CD;
    vr[lane]       = (_Float16)(a0 + (1.f + eps[0]) * xn);
    vr[64 + lane]  = (_Float16)(a1 + (1.f + eps[1]) * xn);
    vr[128 + lane] = (_Float16)(a2 + (1.f + eps[2]) * xn);
}

// --- K4: MLP1(lrelu) + MLP2 via f16 MFMA ------------------------------------
__global__ __launch_bounds__(256) void k_mlp(
    const _Float16* __restrict__ v,
    const float* __restrict__ nw1, const float* __restrict__ nb1,
    const float* __restrict__ nw2, const float* __restrict__ nb2,
    float* __restrict__ out)
{
    __shared__ _Float16 vtile[16][CD + 8];     // stride 400B (16B mult)
    __shared__ _Float16 htile[16][OUT_F + 8];  // stride 272B (16B mult)

    const int tid  = threadIdx.x;
    const int lane = tid & 63;
    const int wid  = tid >> 6;
    const int arow = lane & 15;
    const int kg   = lane >> 4;
    const int o0   = wid * 32;

    half8 w1f[6][2], w2f[4][2];
#pragma unroll
    for (int kk = 0; kk < 6; ++kk)
#pragma unroll
        for (int nt = 0; nt < 2; ++nt) {
            half8 f;
            int colb = o0 + nt * 16 + arow;
            int kb = kk * 32 + kg * 8;
#pragma unroll
            for (int j = 0; j < 8; ++j)
                f[j] = (_Float16)nw1[(size_t)(kb + j) * OUT_F + colb];
            w1f[kk][nt] = f;
        }
#pragma unroll
    for (int kk = 0; kk < 4; ++kk)
#pragma unroll
        for (int nt = 0; nt < 2; ++nt) {
            half8 f;
            int colb = o0 + nt * 16 + arow;
            int kb = kk * 32 + kg * 8;
#pragma unroll
            for (int j = 0; j < 8; ++j)
                f[j] = (_Float16)nw2[(size_t)(kb + j) * OUT_F + colb];
            w2f[kk][nt] = f;
        }

    const float b1a = nb1[o0 + arow],      b1b = nb1[o0 + 16 + arow];
    const float b2a = nb2[o0 + arow],      b2b = nb2[o0 + 16 + arow];

    for (int t = blockIdx.x; t < NTILES; t += gridDim.x) {
        const int nb16 = t * 16;
        __syncthreads();

        for (int i = tid; i < 16 * (CD / 8); i += 256) {    // 384 chunks
            int row = i / (CD / 8), c8 = i % (CD / 8);
            *(half8*)&vtile[row][c8 * 8] =
                *(const half8*)(v + (size_t)(nb16 + row) * CD + c8 * 8);
        }
        __syncthreads();

        f32x4 acc0 = {0.f, 0.f, 0.f, 0.f}, acc1 = {0.f, 0.f, 0.f, 0.f};
#pragma unroll
        for (int kk = 0; kk < 6; ++kk) {
            half8 a = *(const half8*)&vtile[arow][kk * 32 + kg * 8];
            acc0 = __builtin_amdgcn_mfma_f32_16x16x32_f16(a, w1f[kk][0], acc0, 0, 0, 0);
            acc1 = __builtin_amdgcn_mfma_f32_16x16x32_f16(a, w1f[kk][1], acc1, 0, 0, 0);
        }
#pragma unroll
        for (int r = 0; r < 4; ++r) {
            int hr = kg * 4 + r;
            htile[hr][o0 + arow]      = (_Float16)lrelu(acc0[r] + b1a);
            htile[hr][o0 + 16 + arow] = (_Float16)lrelu(acc1[r] + b1b);
        }
        __syncthreads();

        f32x4 c0 = {0.f, 0.f, 0.f, 0.f}, c1 = {0.f, 0.f, 0.f, 0.f};
#pragma unroll
        for (int kk = 0; kk < 4; ++kk) {
            half8 a = *(const half8*)&htile[arow][kk * 32 + kg * 8];
            c0 = __builtin_amdgcn_mfma_f32_16x16x32_f16(a, w2f[kk][0], c0, 0, 0, 0);
            c1 = __builtin_amdgcn_mfma_f32_16x16x32_f16(a, w2f[kk][1], c1, 0, 0, 0);
        }
#pragma unroll
        for (int r = 0; r < 4; ++r) {
            size_t n = (size_t)(nb16 + kg * 4 + r);
            out[n * OUT_F + o0 + arow]      = c0[r] + b2a;
            out[n * OUT_F + o0 + 16 + arow] = c1[r] + b2b;
        }
    }
}

extern "C" void kernel_launch(void* const* d_in, const int* in_sizes, int n_in,
                              void* d_out, int out_size, void* d_ws, size_t ws_size,
                              hipStream_t stream)
{
    const float* x    = (const float*)d_in[0];
    const int*   ei   = (const int*)  d_in[1];
    const float* ea   = (const float*)d_in[2];
    const float* w1   = (const float*)d_in[3];
    const float* b1   = (const float*)d_in[4];
    const float* w2   = (const float*)d_in[5];
    const float* b2   = (const float*)d_in[6];
    const float* eps  = (const float*)d_in[7];
    const float* nw1  = (const float*)d_in[8];
    const float* nb1  = (const float*)d_in[9];
    const float* nw2  = (const float*)d_in[10];
    const float* nb2  = (const float*)d_in[11];
    float* out = (float*)d_out;

    // ws layout (bytes): ~33.2 MB <= proven 38.4 MB
    char* ws = (char*)d_ws;
    int*            bcnt    = (int*)           (ws + 0);         // 784
    int*            offsets = (int*)           (ws + 4096);      // 200,000
    uint2*          brec    = (uint2*)         (ws + 212992);    // 8,028,160
    unsigned char*  bd8     = (unsigned char*) (ws + 8241152);   // 1,003,520
    uint2*          sorted  = (uint2*)         (ws + 9244672);   // 6,400,000
    _Float16*       v       = (_Float16*)      (ws + 15644672);  // 19,200,000

    // xh lives in d_out (6.4 MB of 25.6 MB); dead before k_mlp overwrites
    // (proven safe in rounds 14/18/19/22)
    _Float16* xh = (_Float16*)d_out;

    hipMemsetAsync(bcnt, 0, NBUCK * sizeof(int), stream);

    k_part  <<<EDGEB + XCVT_BLOCKS, 256, 0, stream>>>(
        x, xh, ei, ea, w1, b1, w2, b2, bcnt, brec, bd8);
    k_sortb <<<NBUCK,       256, 0, stream>>>(bcnt, brec, bd8, offsets, sorted);
    k_gather<<<N_NODES / 4, 256, 0, stream>>>(sorted, offsets, xh, eps, v);
    k_mlp   <<<768,         256, 0, stream>>>(v, nw1, nb1, nw2, nb2, out);
}